// Round 8
// baseline (1038.262 us; speedup 1.0000x reference)
//
#include <hip/hip_runtime.h>
#include <hip/hip_bf16.h>
#include <stdint.h>

#define NE 128
#define NI 1856
#define NKK 6
#define NH 512
#define NT 4096
#define CAP 320
#define NPAIR (NT*NKK)
#define LD2I (2*NI)

typedef unsigned short u16;
typedef unsigned int u32;
typedef __attribute__((ext_vector_type(4))) float f32x4;
typedef __attribute__((ext_vector_type(8))) short bf16x8;
typedef __attribute__((ext_vector_type(4))) short s16x4;
typedef const void __attribute__((address_space(1)))* gas1p;
typedef void __attribute__((address_space(3)))* gas3p;

#define SFENCE __builtin_amdgcn_sched_barrier(0)

__device__ __forceinline__ short f2bf(float f) {
  union { __hip_bfloat16 h; short s; } c; c.h = __float2bfloat16(f); return c.s;
}
__device__ __forceinline__ float bf2f(short s) {
  union { float f; unsigned u; } v; v.u = ((unsigned)(u16)s) << 16; return v.f;
}
__device__ __forceinline__ u32 packbf2(float lo, float hi) {
  return (u32)(u16)f2bf(lo) | ((u32)(u16)f2bf(hi) << 16);
}

// physical bid -> logical L clustering consecutive L on one XCD (bijective any n)
__device__ __forceinline__ int xcd_logical(int bid, int n) {
  int q = n >> 3, r = n & 7;
  int xcd = bid & 7, j = bid >> 3;
  return xcd * q + (xcd < r ? xcd : r) + j;
}

// ---------------- routing ----------------
__global__ void k_route(const int* __restrict__ topk, int* __restrict__ counts,
                        int* __restrict__ slot_of_pair, int* __restrict__ pair_of_slot) {
  int n = blockIdx.x * 256 + threadIdx.x;
  if (n >= NPAIR) return;
  int e = topk[n];
  int p = atomicAdd(&counts[e], 1);
  int s = (p < CAP) ? e * CAP + p : -1;
  slot_of_pair[n] = s;
  if (s >= 0) pair_of_slot[s] = n;
}

// ---------------- gather: hidden(f32) -> Xbuf(bf16) ----------------
__global__ void k_gather(const float* __restrict__ hid, const int* __restrict__ counts,
                         const int* __restrict__ pair_of_slot, u16* __restrict__ xbuf) {
  int t = threadIdx.x;
  int row = blockIdx.x * 2 + (t >> 7);
  int c = t & 127;
  int e = row / CAP, p = row % CAP;
  if (p >= counts[e]) return;
  int n = pair_of_slot[row];
  int tok = n / NKK;
  f32x4 v = *(const f32x4*)(hid + (size_t)tok * NH + c * 4);
  s16x4 o;
  o[0] = f2bf(v[0]); o[1] = f2bf(v[1]); o[2] = f2bf(v[2]); o[3] = f2bf(v[3]);
  *(s16x4*)(xbuf + (size_t)row * NH + c * 4) = o;
}

// ============ shared GEMM pieces ============
// A: 256x32 bf16 tile via glld, dbuf 2x16KB @0 (4 glld/wave/iter)
// B: 32k x 64col f32 -> reg (2x dwordx4/thread) -> bf16 col-major LDS
//    [col][k-pair words], XOR swizzle ((col>>2)&3)<<4, dbuf 2x4KB @32768
// B-frag read: ds_read_b128 at col*64 + (kg*16 ^ swz(col))

#define STAGE_A(PITCH, BUF, KT_) do { \
    char* ad_ = lds + (BUF) * 16384; \
    _Pragma("unroll") \
    for (int i_ = 0; i_ < 4; ++i_) { \
      int seg_ = i_ * 4 + w; \
      int o_ = seg_ * 1024 + l * 16; \
      int r_ = o_ >> 6, slot_ = o_ & 63; \
      int grow_ = base + r_; if (grow_ > CAP - 1) grow_ = CAP - 1; \
      const char* g_ = abase + (size_t)grow_ * (PITCH) + (size_t)(KT_) * 64 + (slot_ ^ ((r_ & 3) << 4)); \
      __builtin_amdgcn_global_load_lds((gas1p)g_, (gas3p)(ad_ + seg_ * 1024), 16, 0, 0); \
    } } while (0)

// per-thread B source row pitch differs (LD2I vs NH); bsrc points at (row0,colchunk)
#define LOAD_B(DST, KT_, PITCH) do { \
    const float* p_ = bsrc + (size_t)((KT_) * 32 + kp * 2) * (PITCH); \
    DST[0] = *(const f32x4*)(p_); \
    DST[1] = *(const f32x4*)(p_ + (PITCH)); \
  } while (0)

#define WRITE_B(BUF, SRC) do { \
    char* bb_ = lds + 32768 + (BUF) * 4096; \
    _Pragma("unroll") \
    for (int j_ = 0; j_ < 4; ++j_) { \
      int col_ = c0 + j_; \
      u32 wv_ = packbf2(SRC[0][j_], SRC[1][j_]); \
      *(u32*)(bb_ + col_ * 64 + ((kp * 4) ^ ((col_ >> 2 & 3) << 4))) = wv_; \
    } } while (0)

#define RD_B(P, COL) (*(const bf16x8*)(lds + 32768 + (P) * 4096 + (COL) * 64 + (kg16 ^ (((COL) >> 2 & 3) << 4))))
#define RD_A(P, R) (*(const bf16x8*)(lds + (P) * 16384 + (R) * 64 + (kg16 ^ (((R) & 3) << 4))))

// ======================= GEMM1 =======================
__global__ __launch_bounds__(256, 4) void k_gemm1(
    const u16* __restrict__ xbuf, const float* __restrict__ wgu,
    const int* __restrict__ counts, u16* __restrict__ inter, int e0, int nblk)
{
  __shared__ __align__(16) char lds[40960];
  int L = xcd_logical(blockIdx.x, nblk);
  int el = L / 58, nt = L % 58;
  int e = e0 + el;
  int cnt = counts[e]; if (cnt > CAP) cnt = CAP;
  int n0 = nt * 32;
  int t = threadIdx.x, w = t >> 6, l = t & 63;
  int wm = w >> 1, wc = w & 1;
  const char* abase = (const char*)(xbuf + (size_t)e * CAP * NH);

  // B stage role: k-pair kp=t>>4 (0..15), col-chunk c0=(t&15)*4
  int kp = t >> 4, c0 = (t & 15) * 4;
  int gc = (c0 < 32) ? (n0 + c0) : (NI + n0 + (c0 - 32));
  const float* bsrc = wgu + (size_t)e * NH * LD2I + gc;

  int kg = l >> 4, kg16 = kg * 16;
  int colg = wc * 16 + (l & 15);   // gate panel col 0..31; up = +32

  f32x4 bva[2], bvb[2];

  for (int base = 0; base < cnt; base += 256) {
    __syncthreads();
    f32x4 acc[2][4][2];
    #pragma unroll
    for (int m = 0; m < 2; ++m)
      #pragma unroll
      for (int f = 0; f < 4; ++f) { acc[m][f][0] = (f32x4){0,0,0,0}; acc[m][f][1] = (f32x4){0,0,0,0}; }

    // prologue
    LOAD_B(bva, 0, LD2I);
    STAGE_A(NH*2, 0, 0);
    WRITE_B(0, bva);                 // compiler waits bva regs
    LOAD_B(bvb, 1, LD2I);
    SFENCE; asm volatile("s_waitcnt vmcnt(2) lgkmcnt(0)" ::: "memory"); SFENCE;

    #define G1_ITER(X, CURW, NXT, P) do { \
        SFENCE; __builtin_amdgcn_s_barrier(); SFENCE; \
        { int sk_ = (X)+1 < 16 ? (X)+1 : 15; STAGE_A(NH*2, (P)^1, sk_); } \
        { int lk_ = (X)+2 < 16 ? (X)+2 : 15; LOAD_B(NXT, lk_, LD2I); } \
        WRITE_B((P)^1, CURW); \
        { \
          bf16x8 bg_ = RD_B(P, colg); \
          bf16x8 bu_ = RD_B(P, colg + 32); \
          _Pragma("unroll") \
          for (int mt_ = 0; mt_ < 2; ++mt_) \
            _Pragma("unroll") \
            for (int mf_ = 0; mf_ < 4; ++mf_) { \
              int r_ = mt_ * 128 + wm * 64 + mf_ * 16 + (l & 15); \
              bf16x8 af_ = RD_A(P, r_); \
              acc[mt_][mf_][0] = __builtin_amdgcn_mfma_f32_16x16x32_bf16(af_, bg_, acc[mt_][mf_][0], 0, 0, 0); \
              acc[mt_][mf_][1] = __builtin_amdgcn_mfma_f32_16x16x32_bf16(af_, bu_, acc[mt_][mf_][1], 0, 0, 0); \
            } \
        } \
        SFENCE; asm volatile("s_waitcnt vmcnt(2) lgkmcnt(0)" ::: "memory"); SFENCE; \
      } while (0)

    for (int kt = 0; kt < 16; kt += 2) {
      G1_ITER(kt,     bvb, bva, 0);
      G1_ITER(kt + 1, bva, bvb, 1);
    }
    #undef G1_ITER
    __syncthreads();   // full drain before LDS reuse

    // epilogue: silu(g)*u -> repack rows x 64B -> coalesced stores
    int cl = wc * 16 + (l & 15);
    #pragma unroll
    for (int mt = 0; mt < 2; ++mt)
      #pragma unroll
      for (int mf = 0; mf < 4; ++mf) {
        f32x4 g = acc[mt][mf][0], u = acc[mt][mf][1];
        #pragma unroll
        for (int r = 0; r < 4; ++r) {
          float gv = g[r];
          float val = gv / (1.f + __expf(-gv)) * u[r];
          int rl = mt * 128 + wm * 64 + mf * 16 + (l >> 4) * 4 + r;
          *(short*)(lds + rl * 64 + ((cl * 2) ^ ((rl & 3) << 4))) = f2bf(val);
        }
      }
    __syncthreads();
    int rmax = cnt - base; if (rmax > 256) rmax = 256;
    u16* obase = inter + (size_t)(el * CAP + base) * NI + n0;
    #pragma unroll
    for (int i = 0; i < 4; ++i) {
      int task = i * 256 + t;
      int r = task >> 2, p = task & 3;
      if (r < rmax) {
        bf16x8 v = *(const bf16x8*)(lds + r * 64 + ((p * 16) ^ ((r & 3) << 4)));
        *(bf16x8*)(obase + (size_t)r * NI + p * 8) = v;
      }
    }
  }
}

// ======================= GEMM2 =======================
__global__ __launch_bounds__(256, 4) void k_gemm2(
    const u16* __restrict__ inter, const float* __restrict__ wdn,
    const int* __restrict__ counts, u16* __restrict__ Y, int e0, int nblk)
{
  __shared__ __align__(16) char lds[40960];
  int L = xcd_logical(blockIdx.x, nblk);
  int el = L / 8, nt = L % 8;
  int e = e0 + el;
  int cnt = counts[e]; if (cnt > CAP) cnt = CAP;
  int n0 = nt * 64;
  int t = threadIdx.x, w = t >> 6, l = t & 63;
  int wm = w >> 1, wc = w & 1;
  const char* abase = (const char*)(inter + (size_t)el * CAP * NI);

  int kp = t >> 4, c0 = (t & 15) * 4;
  const float* bsrc = wdn + (size_t)e * NI * NH + n0 + c0;

  int kg = l >> 4, kg16 = kg * 16;
  int col0 = wc * 32 + (l & 15);   // frag0 col; frag1 = +16

  f32x4 bva[2], bvb[2];

  for (int base = 0; base < cnt; base += 256) {
    __syncthreads();
    f32x4 acc[2][4][2];
    #pragma unroll
    for (int m = 0; m < 2; ++m)
      #pragma unroll
      for (int f = 0; f < 4; ++f) { acc[m][f][0] = (f32x4){0,0,0,0}; acc[m][f][1] = (f32x4){0,0,0,0}; }

    LOAD_B(bva, 0, NH);
    STAGE_A(NI*2, 0, 0);
    WRITE_B(0, bva);
    LOAD_B(bvb, 1, NH);
    SFENCE; asm volatile("s_waitcnt vmcnt(2) lgkmcnt(0)" ::: "memory"); SFENCE;

    #define G2_ITER(X, CURW, NXT, P) do { \
        SFENCE; __builtin_amdgcn_s_barrier(); SFENCE; \
        { int sk_ = (X)+1 < 58 ? (X)+1 : 57; STAGE_A(NI*2, (P)^1, sk_); } \
        { int lk_ = (X)+2 < 58 ? (X)+2 : 57; LOAD_B(NXT, lk_, NH); } \
        WRITE_B((P)^1, CURW); \
        { \
          bf16x8 b0_ = RD_B(P, col0); \
          bf16x8 b1_ = RD_B(P, col0 + 16); \
          _Pragma("unroll") \
          for (int mt_ = 0; mt_ < 2; ++mt_) \
            _Pragma("unroll") \
            for (int mf_ = 0; mf_ < 4; ++mf_) { \
              int r_ = mt_ * 128 + wm * 64 + mf_ * 16 + (l & 15); \
              bf16x8 af_ = RD_A(P, r_); \
              acc[mt_][mf_][0] = __builtin_amdgcn_mfma_f32_16x16x32_bf16(af_, b0_, acc[mt_][mf_][0], 0, 0, 0); \
              acc[mt_][mf_][1] = __builtin_amdgcn_mfma_f32_16x16x32_bf16(af_, b1_, acc[mt_][mf_][1], 0, 0, 0); \
            } \
        } \
        SFENCE; asm volatile("s_waitcnt vmcnt(2) lgkmcnt(0)" ::: "memory"); SFENCE; \
      } while (0)

    for (int kt = 0; kt < 58; kt += 2) {
      G2_ITER(kt,     bvb, bva, 0);
      G2_ITER(kt + 1, bva, bvb, 1);
    }
    #undef G2_ITER
    __syncthreads();

    // repack: 256 rows x 128B (64 cols bf16)
    #pragma unroll
    for (int mt = 0; mt < 2; ++mt)
      #pragma unroll
      for (int mf = 0; mf < 4; ++mf)
        #pragma unroll
        for (int f = 0; f < 2; ++f) {
          f32x4 a = acc[mt][mf][f];
          int cl = wc * 32 + f * 16 + (l & 15);
          #pragma unroll
          for (int r = 0; r < 4; ++r) {
            int rl = mt * 128 + wm * 64 + mf * 16 + (l >> 4) * 4 + r;
            *(short*)(lds + rl * 128 + ((cl * 2) ^ ((rl & 7) << 4))) = f2bf(a[r]);
          }
        }
    __syncthreads();
    int rmax = cnt - base; if (rmax > 256) rmax = 256;
    u16* obase = Y + (size_t)(e * CAP + base) * NH + n0;
    #pragma unroll
    for (int i = 0; i < 8; ++i) {
      int task = i * 256 + t;
      int r = task >> 3, p = task & 7;
      if (r < rmax) {
        bf16x8 v = *(const bf16x8*)(lds + r * 128 + ((p * 16) ^ ((r & 7) << 4)));
        *(bf16x8*)(obase + (size_t)r * NH + p * 8) = v;
      }
    }
  }
}

// ---------------- combine ----------------
__global__ void k_combine(const int* __restrict__ slot_of_pair, const float* __restrict__ wts,
                          const u16* __restrict__ Y, float* __restrict__ out)
{
  int t = threadIdx.x;
  int tok = blockIdx.x * 2 + (t >> 7);
  int c = t & 127;
  f32x4 a = (f32x4){0.f, 0.f, 0.f, 0.f};
  #pragma unroll
  for (int k = 0; k < NKK; ++k) {
    int n = tok * NKK + k;
    int s = slot_of_pair[n];
    if (s >= 0) {
      float wv = wts[n];
      s16x4 y = *(const s16x4*)(Y + (size_t)s * NH + c * 4);
      a[0] += wv * bf2f(y[0]);
      a[1] += wv * bf2f(y[1]);
      a[2] += wv * bf2f(y[2]);
      a[3] += wv * bf2f(y[3]);
    }
  }
  *(f32x4*)(out + (size_t)tok * NH + c * 4) = a;
  *(f32x4*)(out + (size_t)(NT + tok) * NH + c * 4) = a;
}

extern "C" void kernel_launch(void* const* d_in, const int* in_sizes, int n_in,
                              void* d_out, int out_size, void* d_ws, size_t ws_size,
                              hipStream_t stream) {
  const float* hid  = (const float*)d_in[0];
  const int*   topk = (const int*)d_in[1];
  const float* wts  = (const float*)d_in[2];
  const float* wgu  = (const float*)d_in[3];
  const float* wdn  = (const float*)d_in[4];

  char* ws = (char*)d_ws;
  size_t off = 0;
  auto alloc = [&](size_t sz) { char* p = ws + off; off = (off + sz + 255) & ~(size_t)255; return p; };
  int* counts        = (int*)alloc(NE * 4);
  int* slot_of_pair  = (int*)alloc((size_t)NPAIR * 4);
  int* pair_of_slot  = (int*)alloc((size_t)NE * CAP * 4);
  u16* xbuf          = (u16*)alloc((size_t)NE * CAP * NH * 2);
  u16* Y             = (u16*)alloc((size_t)NE * CAP * NH * 2);
  size_t remain = ws_size > off ? ws_size - off : 0;
  size_t per_e = (size_t)CAP * NI * 2;
  int chunkE = (int)(remain / per_e);
  if (chunkE > NE) chunkE = NE;
  if (chunkE < 1) chunkE = 1;
  u16* inter = (u16*)(ws + off);

  hipMemsetAsync(counts, 0, NE * 4, stream);
  k_route<<<NPAIR / 256, 256, 0, stream>>>(topk, counts, slot_of_pair, pair_of_slot);
  k_gather<<<NE * CAP / 2, 256, 0, stream>>>(hid, counts, pair_of_slot, xbuf);
  for (int e0 = 0; e0 < NE; e0 += chunkE) {
    int ce = NE - e0 < chunkE ? NE - e0 : chunkE;
    int nb1 = ce * 58;
    int nb2 = ce * 8;
    k_gemm1<<<nb1, 256, 0, stream>>>(xbuf, wgu, counts, inter, e0, nb1);
    k_gemm2<<<nb2, 256, 0, stream>>>(inter, wdn, counts, Y, e0, nb2);
  }
  k_combine<<<NT / 2, 256, 0, stream>>>(slot_of_pair, wts, Y, (float*)d_out);
}

// Round 9
// 571.084 us; speedup vs baseline: 1.8181x; 1.8181x over previous
//
#include <hip/hip_runtime.h>
#include <hip/hip_bf16.h>
#include <stdint.h>

#define NE 128
#define NI 1856
#define NKK 6
#define NH 512
#define NT 4096
#define CAP 320
#define NPAIR (NT*NKK)
#define LD2I (2*NI)

typedef unsigned short u16;
typedef __attribute__((ext_vector_type(4))) float f32x4;
typedef __attribute__((ext_vector_type(8))) short bf16x8;
typedef __attribute__((ext_vector_type(4))) short s16x4;
typedef const void __attribute__((address_space(1)))* gas1p;
typedef void __attribute__((address_space(3)))* gas3p;

#define SFENCE __builtin_amdgcn_sched_barrier(0)

__device__ __forceinline__ short f2bf(float f) {
  union { __hip_bfloat16 h; short s; } c; c.h = __float2bfloat16(f); return c.s;
}
__device__ __forceinline__ float bf2f(short s) {
  union { float f; unsigned u; } v; v.u = ((unsigned)(u16)s) << 16; return v.f;
}

// physical bid -> logical L clustering consecutive L on one XCD (bijective any n)
__device__ __forceinline__ int xcd_logical(int bid, int n) {
  int q = n >> 3, r = n & 7;
  int xcd = bid & 7, j = bid >> 3;
  return xcd * q + (xcd < r ? xcd : r) + j;
}

// ---------------- routing ----------------
__global__ void k_route(const int* __restrict__ topk, int* __restrict__ counts,
                        int* __restrict__ slot_of_pair, int* __restrict__ pair_of_slot) {
  int n = blockIdx.x * 256 + threadIdx.x;
  if (n >= NPAIR) return;
  int e = topk[n];
  int p = atomicAdd(&counts[e], 1);
  int s = (p < CAP) ? e * CAP + p : -1;
  slot_of_pair[n] = s;
  if (s >= 0) pair_of_slot[s] = n;
}

// ---------------- gather: hidden(f32) -> Xbuf(bf16) ----------------
__global__ void k_gather(const float* __restrict__ hid, const int* __restrict__ counts,
                         const int* __restrict__ pair_of_slot, u16* __restrict__ xbuf) {
  int t = threadIdx.x;
  int row = blockIdx.x * 2 + (t >> 7);
  int c = t & 127;
  int e = row / CAP, p = row % CAP;
  if (p >= counts[e]) return;
  int n = pair_of_slot[row];
  int tok = n / NKK;
  f32x4 v = *(const f32x4*)(hid + (size_t)tok * NH + c * 4);
  s16x4 o;
  o[0] = f2bf(v[0]); o[1] = f2bf(v[1]); o[2] = f2bf(v[2]); o[3] = f2bf(v[3]);
  *(s16x4*)(xbuf + (size_t)row * NH + c * 4) = o;
}

// ======================= GEMM1 =======================
// R6 schedule, 8-wave block: X[<=256,512]bf16 @ Wgu[512, 32g+32u]f32 -> silu*up
// 512 thr (8 waves 4Mx2N), BK=32, KT=16. Staging all via global_load_lds:
// per wave per iter exactly 3 ops (2 A + 1 B-f32), triple buffer, stage X+2,
// end-of-iter s_waitcnt vmcnt(3) (drains X+1, leaves X+2 in flight).
__global__ __launch_bounds__(512, 4) void k_gemm1(
    const u16* __restrict__ xbuf, const float* __restrict__ wgu,
    const int* __restrict__ counts, u16* __restrict__ inter, int e0, int nblk)
{
  __shared__ __align__(16) char lds[73728];   // A: 3x16384 @0; B(f32): 3x8192 @49152
  int L = xcd_logical(blockIdx.x, nblk);
  int el = L / 58, nt = L % 58;
  int e = e0 + el;
  int cnt = counts[e]; if (cnt > CAP) cnt = CAP;
  int n0 = nt * 32;
  int t = threadIdx.x, w = t >> 6, l = t & 63;
  int wm = w & 3, wn = w >> 2;
  const char* abase = (const char*)(xbuf + (size_t)e * CAP * NH);

  // B stage: per-lane global src; LDS dest wave-uniform (HW adds lane*16)
  int bks = l >> 4;               // k sub-row 0..3 within this wave's 4-row segment
  int c4 = (l & 15) * 4;          // col chunk (4 f32)
  int gcol = (c4 < 32) ? (n0 + c4) : (NI + n0 + (c4 - 32));
  const float* bsrc = wgu + (size_t)e * NH * LD2I + gcol;

  int kg = l >> 4;                // k-group 0..3 (8 k each)
  int kg16 = kg * 16;
  int colg = wn * 16 + (l & 15);  // gate col 0..31 (up = +32)

  for (int base = 0; base < cnt; base += 256) {
    __syncthreads();

    auto STAGE = [&](int buf, int kt) {
      char* ad = lds + buf * 16384;
      #pragma unroll
      for (int i = 0; i < 2; ++i) {
        int seg = i * 8 + w;                       // 0..15, 1KB each
        int o = seg * 1024 + l * 16;
        int r = o >> 6, slot = o & 63;
        int grow = base + r; if (grow > CAP - 1) grow = CAP - 1;
        const char* g = abase + (size_t)grow * (NH * 2) + kt * 64 + (slot ^ ((r & 3) << 4));
        __builtin_amdgcn_global_load_lds((gas1p)g, (gas3p)(ad + seg * 1024), 16, 0, 0);
      }
      char* bd = lds + 49152 + buf * 8192;
      {
        int seg = w;                               // 0..7 (4 k-rows each)
        int k = seg * 4 + bks;                     // 0..31
        const char* g = (const char*)(bsrc + (size_t)(kt * 32 + k) * LD2I);
        __builtin_amdgcn_global_load_lds((gas1p)g, (gas3p)(bd + seg * 1024), 16, 0, 0);
      }
    };

    f32x4 acc[4][2];
    #pragma unroll
    for (int f = 0; f < 4; ++f) { acc[f][0] = (f32x4){0,0,0,0}; acc[f][1] = (f32x4){0,0,0,0}; }

    STAGE(0, 0);
    STAGE(1, 1);
    SFENCE; asm volatile("s_waitcnt vmcnt(3) lgkmcnt(0)" ::: "memory"); SFENCE;

    for (int kt = 0; kt < 16; ++kt) {
      SFENCE; __builtin_amdgcn_s_barrier(); SFENCE;
      int sk = (kt + 2 < 16) ? kt + 2 : 15;
      STAGE((kt + 2) % 3, sk);

      const char* ab = lds + (kt % 3) * 16384;
      const char* bb = lds + 49152 + (kt % 3) * 8192;
      bf16x8 bg, bu;
      #pragma unroll
      for (int j = 0; j < 8; ++j) {
        int k = kg * 8 + j;
        bg[j] = f2bf(*(const float*)(bb + k * 256 + colg * 4));
        bu[j] = f2bf(*(const float*)(bb + k * 256 + (colg + 32) * 4));
      }
      #pragma unroll
      for (int mf = 0; mf < 4; ++mf) {
        int r = wm * 64 + mf * 16 + (l & 15);
        bf16x8 af = *(const bf16x8*)(ab + r * 64 + (kg16 ^ ((r & 3) << 4)));
        acc[mf][0] = __builtin_amdgcn_mfma_f32_16x16x32_bf16(af, bg, acc[mf][0], 0, 0, 0);
        acc[mf][1] = __builtin_amdgcn_mfma_f32_16x16x32_bf16(af, bu, acc[mf][1], 0, 0, 0);
      }
      SFENCE; asm volatile("s_waitcnt vmcnt(3) lgkmcnt(0)" ::: "memory"); SFENCE;
    }
    __syncthreads();   // full drain; all frag reads done before LDS reuse

    // epilogue: silu(g)*u -> repack rows x 64B -> coalesced stores
    int cl = wn * 16 + (l & 15);
    #pragma unroll
    for (int mf = 0; mf < 4; ++mf) {
      f32x4 g = acc[mf][0], u = acc[mf][1];
      #pragma unroll
      for (int r = 0; r < 4; ++r) {
        float gv = g[r];
        float val = gv / (1.f + __expf(-gv)) * u[r];
        int rl = wm * 64 + mf * 16 + (l >> 4) * 4 + r;
        *(short*)(lds + rl * 64 + ((cl * 2) ^ ((rl & 3) << 4))) = f2bf(val);
      }
    }
    __syncthreads();
    int rmax = cnt - base; if (rmax > 256) rmax = 256;
    u16* obase = inter + (size_t)(el * CAP + base) * NI + n0;
    #pragma unroll
    for (int i = 0; i < 2; ++i) {
      int task = i * 512 + t;              // 1024 tasks = 256 rows x 4 parts
      int r = task >> 2, p = task & 3;
      if (r < rmax) {
        bf16x8 v = *(const bf16x8*)(lds + r * 64 + ((p * 16) ^ ((r & 3) << 4)));
        *(bf16x8*)(obase + (size_t)r * NI + p * 8) = v;
      }
    }
  }
}

// ======================= GEMM2 =======================
// inter[<=256,1856]bf16 @ Wdn[1856,64]f32 -> Y bf16; KT=58, same 8-wave schedule
__global__ __launch_bounds__(512, 4) void k_gemm2(
    const u16* __restrict__ inter, const float* __restrict__ wdn,
    const int* __restrict__ counts, u16* __restrict__ Y, int e0, int nblk)
{
  __shared__ __align__(16) char lds[73728];
  int L = xcd_logical(blockIdx.x, nblk);
  int el = L / 8, nt = L % 8;
  int e = e0 + el;
  int cnt = counts[e]; if (cnt > CAP) cnt = CAP;
  int n0 = nt * 64;
  int t = threadIdx.x, w = t >> 6, l = t & 63;
  int wm = w & 3, wn = w >> 2;
  const char* abase = (const char*)(inter + (size_t)el * CAP * NI);

  int bks = l >> 4;
  int c4 = (l & 15) * 4;
  const float* bsrc = wdn + (size_t)e * NI * NH + n0 + c4;

  int kg = l >> 4;
  int kg16 = kg * 16;
  int col0 = wn * 32 + (l & 15);   // frag0 col; frag1 = +16

  for (int base = 0; base < cnt; base += 256) {
    __syncthreads();

    auto STAGE = [&](int buf, int kt) {
      char* ad = lds + buf * 16384;
      #pragma unroll
      for (int i = 0; i < 2; ++i) {
        int seg = i * 8 + w;
        int o = seg * 1024 + l * 16;
        int r = o >> 6, slot = o & 63;
        int grow = base + r; if (grow > CAP - 1) grow = CAP - 1;
        const char* g = abase + (size_t)grow * (NI * 2) + kt * 64 + (slot ^ ((r & 3) << 4));
        __builtin_amdgcn_global_load_lds((gas1p)g, (gas3p)(ad + seg * 1024), 16, 0, 0);
      }
      char* bd = lds + 49152 + buf * 8192;
      {
        int seg = w;
        int k = seg * 4 + bks;
        const char* g = (const char*)(bsrc + (size_t)(kt * 32 + k) * NH);
        __builtin_amdgcn_global_load_lds((gas1p)g, (gas3p)(bd + seg * 1024), 16, 0, 0);
      }
    };

    f32x4 acc[4][2];
    #pragma unroll
    for (int f = 0; f < 4; ++f) { acc[f][0] = (f32x4){0,0,0,0}; acc[f][1] = (f32x4){0,0,0,0}; }

    STAGE(0, 0);
    STAGE(1, 1);
    SFENCE; asm volatile("s_waitcnt vmcnt(3) lgkmcnt(0)" ::: "memory"); SFENCE;

    for (int kt = 0; kt < 58; ++kt) {
      SFENCE; __builtin_amdgcn_s_barrier(); SFENCE;
      int sk = (kt + 2 < 58) ? kt + 2 : 57;
      STAGE((kt + 2) % 3, sk);

      const char* ab = lds + (kt % 3) * 16384;
      const char* bb = lds + 49152 + (kt % 3) * 8192;
      bf16x8 b0, b1;
      #pragma unroll
      for (int j = 0; j < 8; ++j) {
        int k = kg * 8 + j;
        b0[j] = f2bf(*(const float*)(bb + k * 256 + col0 * 4));
        b1[j] = f2bf(*(const float*)(bb + k * 256 + (col0 + 16) * 4));
      }
      #pragma unroll
      for (int mf = 0; mf < 4; ++mf) {
        int r = wm * 64 + mf * 16 + (l & 15);
        bf16x8 af = *(const bf16x8*)(ab + r * 64 + (kg16 ^ ((r & 3) << 4)));
        acc[mf][0] = __builtin_amdgcn_mfma_f32_16x16x32_bf16(af, b0, acc[mf][0], 0, 0, 0);
        acc[mf][1] = __builtin_amdgcn_mfma_f32_16x16x32_bf16(af, b1, acc[mf][1], 0, 0, 0);
      }
      SFENCE; asm volatile("s_waitcnt vmcnt(3) lgkmcnt(0)" ::: "memory"); SFENCE;
    }
    __syncthreads();

    // repack: 256 rows x 128B (64 cols bf16)
    #pragma unroll
    for (int mf = 0; mf < 4; ++mf)
      #pragma unroll
      for (int f = 0; f < 2; ++f) {
        f32x4 a = acc[mf][f];
        int cl = wn * 32 + f * 16 + (l & 15);
        #pragma unroll
        for (int r = 0; r < 4; ++r) {
          int rl = wm * 64 + mf * 16 + (l >> 4) * 4 + r;
          *(short*)(lds + rl * 128 + ((cl * 2) ^ ((rl & 7) << 4))) = f2bf(a[r]);
        }
      }
    __syncthreads();
    int rmax = cnt - base; if (rmax > 256) rmax = 256;
    u16* obase = Y + (size_t)(e * CAP + base) * NH + n0;
    #pragma unroll
    for (int i = 0; i < 4; ++i) {
      int task = i * 512 + t;              // 2048 tasks = 256 rows x 8 parts
      int r = task >> 3, p = task & 7;
      if (r < rmax) {
        bf16x8 v = *(const bf16x8*)(lds + r * 128 + ((p * 16) ^ ((r & 7) << 4)));
        *(bf16x8*)(obase + (size_t)r * NH + p * 8) = v;
      }
    }
  }
}

// ---------------- combine ----------------
__global__ void k_combine(const int* __restrict__ slot_of_pair, const float* __restrict__ wts,
                          const u16* __restrict__ Y, float* __restrict__ out)
{
  int t = threadIdx.x;
  int tok = blockIdx.x * 2 + (t >> 7);
  int c = t & 127;
  f32x4 a = (f32x4){0.f, 0.f, 0.f, 0.f};
  #pragma unroll
  for (int k = 0; k < NKK; ++k) {
    int n = tok * NKK + k;
    int s = slot_of_pair[n];
    if (s >= 0) {
      float wv = wts[n];
      s16x4 y = *(const s16x4*)(Y + (size_t)s * NH + c * 4);
      a[0] += wv * bf2f(y[0]);
      a[1] += wv * bf2f(y[1]);
      a[2] += wv * bf2f(y[2]);
      a[3] += wv * bf2f(y[3]);
    }
  }
  *(f32x4*)(out + (size_t)tok * NH + c * 4) = a;
  *(f32x4*)(out + (size_t)(NT + tok) * NH + c * 4) = a;
}

extern "C" void kernel_launch(void* const* d_in, const int* in_sizes, int n_in,
                              void* d_out, int out_size, void* d_ws, size_t ws_size,
                              hipStream_t stream) {
  const float* hid  = (const float*)d_in[0];
  const int*   topk = (const int*)d_in[1];
  const float* wts  = (const float*)d_in[2];
  const float* wgu  = (const float*)d_in[3];
  const float* wdn  = (const float*)d_in[4];

  char* ws = (char*)d_ws;
  size_t off = 0;
  auto alloc = [&](size_t sz) { char* p = ws + off; off = (off + sz + 255) & ~(size_t)255; return p; };
  int* counts        = (int*)alloc(NE * 4);
  int* slot_of_pair  = (int*)alloc((size_t)NPAIR * 4);
  int* pair_of_slot  = (int*)alloc((size_t)NE * CAP * 4);
  u16* xbuf          = (u16*)alloc((size_t)NE * CAP * NH * 2);
  u16* Y             = (u16*)alloc((size_t)NE * CAP * NH * 2);
  size_t remain = ws_size > off ? ws_size - off : 0;
  size_t per_e = (size_t)CAP * NI * 2;
  int chunkE = (int)(remain / per_e);
  if (chunkE > NE) chunkE = NE;
  if (chunkE < 1) chunkE = 1;
  u16* inter = (u16*)(ws + off);

  hipMemsetAsync(counts, 0, NE * 4, stream);
  k_route<<<NPAIR / 256, 256, 0, stream>>>(topk, counts, slot_of_pair, pair_of_slot);
  k_gather<<<NE * CAP / 2, 256, 0, stream>>>(hid, counts, pair_of_slot, xbuf);
  for (int e0 = 0; e0 < NE; e0 += chunkE) {
    int ce = NE - e0 < chunkE ? NE - e0 : chunkE;
    int nb1 = ce * 58;
    int nb2 = ce * 8;
    k_gemm1<<<nb1, 512, 0, stream>>>(xbuf, wgu, counts, inter, e0, nb1);
    k_gemm2<<<nb2, 512, 0, stream>>>(inter, wdn, counts, Y, e0, nb2);
  }
  k_combine<<<NT / 2, 256, 0, stream>>>(slot_of_pair, wts, Y, (float*)d_out);
}